// Round 13
// baseline (178.512 us; speedup 1.0000x reference)
//
#include <hip/hip_runtime.h>
#include <hip/hip_bf16.h>

#define Bq 2
#define Tq 2048
#define Dq 1024
#define Hq 16
#define HDq 64

typedef __attribute__((ext_vector_type(8))) short short8;
typedef __attribute__((ext_vector_type(4))) float f32x4;

__device__ __forceinline__ unsigned short f2bf(float f) {
  union { float f; unsigned int i; } v; v.f = f;
  unsigned int r = v.i + 0x7fffu + ((v.i >> 16) & 1u);
  return (unsigned short)(r >> 16);
}

// convert 8 contiguous fp32 -> short8 of bf16 bits
__device__ __forceinline__ short8 cvt8(const float* __restrict__ g) {
  const float4* gp = (const float4*)g;
  float4 x0 = gp[0], x1 = gp[1];
  short8 v;
  v[0] = (short)f2bf(x0.x); v[1] = (short)f2bf(x0.y);
  v[2] = (short)f2bf(x0.z); v[3] = (short)f2bf(x0.w);
  v[4] = (short)f2bf(x1.x); v[5] = (short)f2bf(x1.y);
  v[6] = (short)f2bf(x1.z); v[7] = (short)f2bf(x1.w);
  return v;
}

// async 16B global -> LDS (lands at wave-uniform base + lane*16)
__device__ __forceinline__ void async_cp16(const void* g, void* l) {
  __builtin_amdgcn_global_load_lds(
      (const __attribute__((address_space(1))) void*)g,
      (__attribute__((address_space(3))) void*)l, 16, 0, 0);
}

// permlane pair-swap (see derivation at attn kernel)
__device__ __forceinline__ void permswap(unsigned &a, unsigned &b) {
  asm("v_permlane32_swap_b32 %0, %1" : "+v"(a), "+v"(b));
  asm("v_permlane16_swap_b32 %0, %1" : "+v"(a), "+v"(b));
}

// ---------------- bf16 pre-convert: x, w_qkv, w_proj --------------------
constexpr int NXC = (Bq * Tq * Dq) / 8;       // 524288 chunks of 8
constexpr int NW1C = (3 * Dq * Dq) / 8;       // 393216
constexpr int NW2C = (Dq * Dq) / 8;           // 131072

// softmax scale folded into Q at QKV-GEMM epilogue: 1/sqrt(64) * log2(e)
#define QSCL 0.18033688011112042f

// 16 floats/thread (64B in, 32B out) — G13 vectorize (R10, kept).
__global__ __launch_bounds__(256)
void cvt_all(const float* __restrict__ x, const float* __restrict__ w1,
             const float* __restrict__ w2, unsigned short* __restrict__ xo,
             unsigned short* __restrict__ w1o, unsigned short* __restrict__ w2o)
{
  constexpr int NX16 = NXC / 2, NW116 = NW1C / 2, NW216 = NW2C / 2;
  int i = blockIdx.x * 256 + threadIdx.x;      // chunk of 16 floats
  const float* src; unsigned short* dst; int j;
  if (i < NX16)               { src = x;  dst = xo;  j = i; }
  else if (i < NX16 + NW116)  { src = w1; dst = w1o; j = i - NX16; }
  else                        { src = w2; dst = w2o; j = i - NX16 - NW116; }
  *(short8*)&dst[(size_t)j * 16]     = cvt8(src + (size_t)j * 16);
  *(short8*)&dst[(size_t)j * 16 + 8] = cvt8(src + (size_t)j * 16 + 8);
}

// ---------------- GEMM: C[M,N] = A[M,K] @ W[N,K]^T + bias ----------------
// m97 structure, BK=64 as two 32-col panels, SINGLE-buffered — CONFIRMED
// local optimum for the loop itself: 8-phase slower twice (R2/R3),
// ping-pong+swizzle slower (R11, even with conflicts 3.1M->0).
// R13: QKV tile 128x128 -> 64x128 (grid 24x64 = 1536 blocks = 6/CU).
// Grounds: R4 measured on proj (same structure, same K) that 64x128@2/CU
// beats 128x128@1/CU — resident-block drain coverage beats per-tile
// MFMA-per-byte for this latency-bound loop. QKV at 3/CU shows the same
// starved signature (Occ 29%, MfmaUtil 19.6%). LDS 24KB -> 6 blocks/CU.
// MAP: XCD-tiled bijective remaps (launch id mod 8 = XCD, validated R7):
//   MAP=3 QKV 24x64:  12n x 16m per XCD (A 2MB + B 3MB ~ L2)
//   MAP=2 proj 8x64:  all-n x 8m per XCD (A 1MB + B 2MB fits)
template<int EPI, int BM_, int BN_, int MAP>
__global__ __launch_bounds__(256)
void gemm_bt(const unsigned short* __restrict__ Ab, const unsigned short* __restrict__ Wb,
             const float* __restrict__ bias, float* __restrict__ outp,
             int K, int N,
             unsigned short* __restrict__ qo, unsigned short* __restrict__ ko,
             unsigned short* __restrict__ vo)
{
  constexpr int WM = BM_ / 2, WN = BN_ / 2;
  constexpr int NI = WM / 16;          // A-frags / acc rows per wave
  constexpr int NJ = WN / 16;          // B-frags / acc cols per wave
  constexpr int NAI = BM_ / 32;        // A staging issues/thread
  constexpr int NBI = BN_ / 32;        // B staging issues/thread
  __shared__ unsigned short As[2 * BM_ * 32];   // [panel][row][col]
  __shared__ unsigned short Bs[2 * BN_ * 32];

  const int t = threadIdx.x;
  const int lane = t & 63, w = t >> 6;

  // XCD-tiled bijective block remap (launch id mod 8 = XCD, validated R7).
  int bx = (int)blockIdx.x, by = (int)blockIdx.y;
  if (MAP == 3) {                      // QKV 64x128: 24x64 grid -> 12n x 16m/XCD
    int lin = by * 24 + bx;
    int c = lin & 7, u = lin >> 3;     // u in [0,192)
    bx = (c & 1) * 12 + (u % 12);
    by = (c >> 1) * 16 + (u / 12);
  } else if (MAP == 2) {               // proj: 8x64 grid -> 8m x all-n per XCD
    int lin = by * 8 + bx;
    int c = lin & 7, u = lin >> 3;     // u in [0,64)
    by = c * 8 + (u & 7);
    bx = u >> 3;
  }
  const int m0 = by * BM_, n0 = bx * BN_;
  const int fr = lane & 15, qd = lane >> 4;
  const int wm = (w >> 1) * WM, wn = (w & 1) * WN;

  f32x4 acc[NI][NJ] = {};

  for (int k0 = 0; k0 < K; k0 += 64) {
    __syncthreads();
    #pragma unroll
    for (int j = 0; j < NAI; j++) {          // A: BM_*8 granules of 16B
      int G = j * 256 + t;
      int panel = G / (BM_ * 4), rowg = (G / 4) % BM_, colg = G & 3;
      async_cp16(Ab + (size_t)(m0 + rowg) * K + k0 + panel * 32 + colg * 8, &As[G * 8]);
    }
    #pragma unroll
    for (int j = 0; j < NBI; j++) {          // B: BN_*8 granules
      int G = j * 256 + t;
      int panel = G / (BN_ * 4), rowg = (G / 4) % BN_, colg = G & 3;
      async_cp16(Wb + (size_t)(n0 + rowg) * K + k0 + panel * 32 + colg * 8, &Bs[G * 8]);
    }
    __syncthreads();
    #pragma unroll
    for (int kh = 0; kh < 2; kh++) {
      short8 af[NI], bf[NJ];
      #pragma unroll
      for (int ib = 0; ib < NI; ib++)
        af[ib] = *(const short8*)&As[kh * (BM_ * 32) + (wm + ib * 16 + fr) * 32 + qd * 8];
      #pragma unroll
      for (int jb = 0; jb < NJ; jb++)
        bf[jb] = *(const short8*)&Bs[kh * (BN_ * 32) + (wn + jb * 16 + fr) * 32 + qd * 8];
      #pragma unroll
      for (int ib = 0; ib < NI; ib++)
        #pragma unroll
        for (int jb = 0; jb < NJ; jb++)
          acc[ib][jb] = __builtin_amdgcn_mfma_f32_16x16x32_bf16(af[ib], bf[jb], acc[ib][jb], 0, 0, 0);
    }
  }

  #pragma unroll
  for (int jb = 0; jb < NJ; jb++) {
    int col = n0 + wn + jb * 16 + fr;
    float bv = bias[col];
    if (EPI == 0) {
      int which = col >> 10;       // uniform per block (BN divides 1024)
      int rem = col & 1023;
      int hh = rem >> 6, dd = rem & 63;
      #pragma unroll
      for (int ib = 0; ib < NI; ib++) {
        int row4 = m0 + wm + ib * 16 + qd * 4;
        int bb = row4 >> 11, tt = row4 & (Tq - 1);
        if (which == 2) {
          unsigned lo = (unsigned)f2bf(acc[ib][jb][0] + bv)
                      | ((unsigned)f2bf(acc[ib][jb][1] + bv) << 16);
          unsigned hi = (unsigned)f2bf(acc[ib][jb][2] + bv)
                      | ((unsigned)f2bf(acc[ib][jb][3] + bv) << 16);
          uint2 pk; pk.x = lo; pk.y = hi;
          *(uint2*)&vo[((size_t)(bb * Hq + hh) * HDq + dd) * Tq + tt] = pk;
        } else {
          unsigned short* dst = (which == 0) ? qo : ko;
          float scl = (which == 0) ? QSCL : 1.0f;
          #pragma unroll
          for (int r = 0; r < 4; r++)
            dst[((size_t)(bb * Hq + hh) * Tq + tt + r) * HDq + dd] =
                f2bf((acc[ib][jb][r] + bv) * scl);
        }
      }
    } else {
      #pragma unroll
      for (int ib = 0; ib < NI; ib++)
        #pragma unroll
        for (int r = 0; r < 4; r++) {
          int row = m0 + wm + ib * 16 + qd * 4 + r;
          outp[(size_t)row * N + col] = acc[ib][jb][r] + bv;
        }
    }
  }
}

// ---------------- MFMA flash attention: in-register softmax ------------------
// R7 kernel (best measured: ~42us). Structure log: dual-strip 2/CU = 56.8us
// twice (R0,R5); balance remap no-op (R6); split-K w/ device fences disaster
// (R8); no-LDS direct-global 125us (R9 — L1 thrash). ONE 64-row strip per
// block, 1024 blocks = 4/CU; XCD-grouped bh keeps K/V L2-resident (R7:
// FETCH 63->12MB). Swapped QK^T + cvt_pk/permlane in-register softmax;
// P never touches LDS.

template<bool DIAG>
__device__ __forceinline__ void strip_iter(
    const unsigned short* __restrict__ Ksb, const unsigned short* __restrict__ Vtsb,
    const short8 (&aq)[2], const short8 ones,
    int fr, int qd, int off0, int off1, int thr,
    f32x4 (&oacc)[4], f32x4& lacc)
{
  short8 bk[4][2];
  #pragma unroll
  for (int nb = 0; nb < 4; nb++) {
    bk[nb][0] = *(const short8*)&Ksb[(nb * 16 + fr) * 64 + off0];
    bk[nb][1] = *(const short8*)&Ksb[(nb * 16 + fr) * 64 + off1];
  }
  f32x4 s4[4] = {};
  __builtin_amdgcn_s_setprio(1);
  #pragma unroll
  for (int nb = 0; nb < 4; nb++)
    s4[nb] = __builtin_amdgcn_mfma_f32_16x16x32_bf16(bk[nb][0], aq[0], s4[nb], 0, 0, 0);
  #pragma unroll
  for (int nb = 0; nb < 4; nb++)
    s4[nb] = __builtin_amdgcn_mfma_f32_16x16x32_bf16(bk[nb][1], aq[1], s4[nb], 0, 0, 0);
  __builtin_amdgcn_s_setprio(0);

  unsigned x[4][2];
  #pragma unroll
  for (int nb = 0; nb < 4; nb++) {
    float p[4];
    #pragma unroll
    for (int reg = 0; reg < 4; reg++) {
      p[reg] = exp2f(s4[nb][reg]);
      if (DIAG && (nb * 16 + qd * 4 + reg) > thr) p[reg] = 0.f;
    }
    asm("v_cvt_pk_bf16_f32 %0, %1, %2" : "=v"(x[nb][0]) : "v"(p[0]), "v"(p[1]));
    asm("v_cvt_pk_bf16_f32 %0, %1, %2" : "=v"(x[nb][1]) : "v"(p[2]), "v"(p[3]));
  }
  permswap(x[0][0], x[1][0]);
  permswap(x[0][1], x[1][1]);
  permswap(x[2][0], x[3][0]);
  permswap(x[2][1], x[3][1]);

  short8 ap0, ap1;
  {
    union { unsigned u[4]; short8 s; } c0, c1;
    c0.u[0] = x[0][0]; c0.u[1] = x[0][1]; c0.u[2] = x[1][0]; c0.u[3] = x[1][1];
    c1.u[0] = x[2][0]; c1.u[1] = x[2][1]; c1.u[2] = x[3][0]; c1.u[3] = x[3][1];
    ap0 = c0.s; ap1 = c1.s;
  }

  short8 bv[4][2];
  #pragma unroll
  for (int db = 0; db < 4; db++) {
    bv[db][0] = *(const short8*)&Vtsb[(db * 16 + fr) * 64 + off0];
    bv[db][1] = *(const short8*)&Vtsb[(db * 16 + fr) * 64 + off1];
  }
  __builtin_amdgcn_s_setprio(1);
  lacc = __builtin_amdgcn_mfma_f32_16x16x32_bf16(ap0, ones, lacc, 0, 0, 0);
  lacc = __builtin_amdgcn_mfma_f32_16x16x32_bf16(ap1, ones, lacc, 0, 0, 0);
  #pragma unroll
  for (int db = 0; db < 4; db++) {
    oacc[db] = __builtin_amdgcn_mfma_f32_16x16x32_bf16(ap0, bv[db][0], oacc[db], 0, 0, 0);
    oacc[db] = __builtin_amdgcn_mfma_f32_16x16x32_bf16(ap1, bv[db][1], oacc[db], 0, 0, 0);
  }
  __builtin_amdgcn_s_setprio(0);
}

__global__ __launch_bounds__(256, 4)
void attn_fwd(const unsigned short* __restrict__ qb, const unsigned short* __restrict__ kb,
              const unsigned short* __restrict__ vtb, unsigned short* __restrict__ ab)
{
  __shared__ unsigned short Ks[2][64 * 64];    // 2 x 8 KB, swizzled
  __shared__ unsigned short Vts[2][64 * 64];   // 2 x 8 KB, swizzled (V^T [d][c])

  const int t = threadIdx.x, w = t >> 6, lane = t & 63;
  const int fr = lane & 15, qd = lane >> 4;

  // XCD-grouped (bh, strip) assignment (validated R7: K/V L2-resident).
  const int L  = (int)blockIdx.x;              // 0..1023
  const int c  = L & 7;                        // XCD (launch id mod 8)
  const int i  = L >> 3;                       // 0..127 within XCD
  const int q4 = i >> 5, j = i & 31;
  const int bh = c + 8 * q4;                   // 4 bh per XCD -> K/V L2-fit
  const int s  = (q4 & 1) ? j : 31 - j;        // balanced, long strips early
  const int s0 = s * 64;
  const int thr = w * 16 + fr;                 // this lane's q (strip-local)

  short8 aq[2];
  const unsigned short* Qg = qb + ((size_t)bh * Tq + s0) * HDq;
  #pragma unroll
  for (int cc = 0; cc < 2; cc++)
    aq[cc] = *(const short8*)(Qg + (w * 16 + fr) * 64 + cc * 32 + qd * 8);

  const unsigned short* Kbh = kb + (size_t)bh * Tq * HDq;
  const unsigned short* Vbh = vtb + (size_t)bh * HDq * Tq;

  const int off0 = ((qd ^ (fr & 7)) * 8);
  const int off1 = off0 ^ 32;

  const int G0 = 2 * w * 64 + lane, G1 = G0 + 64;
  const int r0 = G0 >> 3, g0 = (G0 & 7) ^ (r0 & 7);
  const int r1 = G1 >> 3, g1 = (G1 & 7) ^ (r1 & 7);

  short8 ones;
  #pragma unroll
  for (int jj = 0; jj < 8; jj++) ones[jj] = (short)0x3F80;  // bf16 1.0

  f32x4 oacc[4] = {};
  f32x4 lacc = {};

  async_cp16(Kbh + (size_t)r0 * 64 + g0 * 8, &Ks[0][G0 * 8]);
  async_cp16(Vbh + (size_t)r0 * Tq + g0 * 8, &Vts[0][G0 * 8]);
  async_cp16(Kbh + (size_t)r1 * 64 + g1 * 8, &Ks[0][G1 * 8]);
  async_cp16(Vbh + (size_t)r1 * Tq + g1 * 8, &Vts[0][G1 * 8]);

  for (int kt = 0; kt < s; kt++) {
    const int cur = kt & 1, nxt = cur ^ 1;
    __syncthreads();   // drains buf[cur] loads (in flight during prior compute)
    const size_t kofs = (size_t)(kt + 1) * 64;
    async_cp16(Kbh + (kofs + r0) * 64 + g0 * 8, &Ks[nxt][G0 * 8]);
    async_cp16(Vbh + (size_t)r0 * Tq + kofs + g0 * 8, &Vts[nxt][G0 * 8]);
    async_cp16(Kbh + (kofs + r1) * 64 + g1 * 8, &Ks[nxt][G1 * 8]);
    async_cp16(Vbh + (size_t)r1 * Tq + kofs + g1 * 8, &Vts[nxt][G1 * 8]);
    strip_iter<false>(Ks[cur], Vts[cur], aq, ones, fr, qd, off0, off1, thr, oacc, lacc);
  }
  __syncthreads();
  strip_iter<true>(Ks[s & 1], Vts[s & 1], aq, ones, fr, qd, off0, off1, thr, oacc, lacc);

  #pragma unroll
  for (int reg = 0; reg < 4; reg++) {
    float linv = 1.0f / lacc[reg];
    size_t rowoff = ((size_t)(bh >> 4) * Tq + s0 + w * 16 + qd * 4 + reg) * Dq
                  + (bh & 15) * HDq;
    #pragma unroll
    for (int db = 0; db < 4; db++)
      ab[rowoff + db * 16 + fr] = f2bf(oacc[db][reg] * linv);
  }
}

extern "C" void kernel_launch(void* const* d_in, const int* in_sizes, int n_in,
                              void* d_out, int out_size, void* d_ws, size_t ws_size,
                              hipStream_t stream) {
  const float* x      = (const float*)d_in[0];
  const float* w_qkv  = (const float*)d_in[1];
  const float* b_qkv  = (const float*)d_in[2];
  const float* w_proj = (const float*)d_in[3];
  const float* b_proj = (const float*)d_in[4];
  float* out = (float*)d_out;

  unsigned short* ws = (unsigned short*)d_ws;
  const size_t NE = (size_t)Bq * Hq * Tq * HDq;   // 4,194,304
  unsigned short* qb  = ws;
  unsigned short* kb  = ws + NE;
  unsigned short* vtb = ws + 2 * NE;   // V^T: [B,H,HD,T]
  unsigned short* ab  = ws + 3 * NE;
  unsigned short* xb  = ws + 4 * NE;             // bf16 x      [4096,1024]
  unsigned short* wqb = xb + (size_t)NXC * 8;    // bf16 w_qkv  [3072,1024]
  unsigned short* wpb = wqb + (size_t)NW1C * 8;  // bf16 w_proj [1024,1024]

  dim3 blk(256);
  cvt_all<<<dim3((NXC + NW1C + NW2C) >> 9), blk, 0, stream>>>(x, w_qkv, w_proj, xb, wqb, wpb);

  dim3 g1(3 * Dq / 128, Bq * Tq / 64);    // 24 x 64 (QKV: 64x128, 6 blk/CU)
  gemm_bt<0, 64, 128, 3><<<g1, blk, 0, stream>>>(xb, wqb, b_qkv, nullptr,
                                                 Dq, 3 * Dq, qb, kb, vtb);

  dim3 g2(1024);                          // XCD-grouped bh (R7, best measured)
  attn_fwd<<<g2, blk, 0, stream>>>(qb, kb, vtb, ab);

  dim3 g3(Dq / 128, Bq * Tq / 64);        // 8 x 64  (proj: 64x128, XCD-tiled)
  gemm_bt<1, 64, 128, 2><<<g3, blk, 0, stream>>>(ab, wpb, b_proj, out,
                                                 Dq, Dq, nullptr, nullptr, nullptr);
}

// Round 14
// 171.244 us; speedup vs baseline: 1.0424x; 1.0424x over previous
//
#include <hip/hip_runtime.h>
#include <hip/hip_bf16.h>

#define Bq 2
#define Tq 2048
#define Dq 1024
#define Hq 16
#define HDq 64

typedef __attribute__((ext_vector_type(8))) short short8;
typedef __attribute__((ext_vector_type(4))) float f32x4;

__device__ __forceinline__ unsigned short f2bf(float f) {
  union { float f; unsigned int i; } v; v.f = f;
  unsigned int r = v.i + 0x7fffu + ((v.i >> 16) & 1u);
  return (unsigned short)(r >> 16);
}

// convert 8 contiguous fp32 -> short8 of bf16 bits
__device__ __forceinline__ short8 cvt8(const float* __restrict__ g) {
  const float4* gp = (const float4*)g;
  float4 x0 = gp[0], x1 = gp[1];
  short8 v;
  v[0] = (short)f2bf(x0.x); v[1] = (short)f2bf(x0.y);
  v[2] = (short)f2bf(x0.z); v[3] = (short)f2bf(x0.w);
  v[4] = (short)f2bf(x1.x); v[5] = (short)f2bf(x1.y);
  v[6] = (short)f2bf(x1.z); v[7] = (short)f2bf(x1.w);
  return v;
}

// async 16B global -> LDS (lands at wave-uniform base + lane*16)
__device__ __forceinline__ void async_cp16(const void* g, void* l) {
  __builtin_amdgcn_global_load_lds(
      (const __attribute__((address_space(1))) void*)g,
      (__attribute__((address_space(3))) void*)l, 16, 0, 0);
}

// permlane pair-swap (see derivation at attn kernel)
__device__ __forceinline__ void permswap(unsigned &a, unsigned &b) {
  asm("v_permlane32_swap_b32 %0, %1" : "+v"(a), "+v"(b));
  asm("v_permlane16_swap_b32 %0, %1" : "+v"(a), "+v"(b));
}

// ---------------- bf16 pre-convert: x, w_qkv, w_proj --------------------
constexpr int NXC = (Bq * Tq * Dq) / 8;       // 524288 chunks of 8
constexpr int NW1C = (3 * Dq * Dq) / 8;       // 393216
constexpr int NW2C = (Dq * Dq) / 8;           // 131072

// softmax scale folded into Q at QKV-GEMM epilogue: 1/sqrt(64) * log2(e)
#define QSCL 0.18033688011112042f

// 16 floats/thread (64B in, 32B out) — G13 vectorize (R10, kept).
__global__ __launch_bounds__(256)
void cvt_all(const float* __restrict__ x, const float* __restrict__ w1,
             const float* __restrict__ w2, unsigned short* __restrict__ xo,
             unsigned short* __restrict__ w1o, unsigned short* __restrict__ w2o)
{
  constexpr int NX16 = NXC / 2, NW116 = NW1C / 2, NW216 = NW2C / 2;
  int i = blockIdx.x * 256 + threadIdx.x;      // chunk of 16 floats
  const float* src; unsigned short* dst; int j;
  if (i < NX16)               { src = x;  dst = xo;  j = i; }
  else if (i < NX16 + NW116)  { src = w1; dst = w1o; j = i - NX16; }
  else                        { src = w2; dst = w2o; j = i - NX16 - NW116; }
  *(short8*)&dst[(size_t)j * 16]     = cvt8(src + (size_t)j * 16);
  *(short8*)&dst[(size_t)j * 16 + 8] = cvt8(src + (size_t)j * 16 + 8);
}

// ---------------- GEMM: C[M,N] = A[M,K] @ W[N,K]^T + bias ----------------
// m97 structure, BK=64 as two 32-col panels, SINGLE-buffered — CONFIRMED
// local optimum: 8-phase slower twice (R2/R3), ping-pong+swizzle slower
// (R11, conflicts 3.1M->0 yet slower: conflicts latency-hidden), 64x128
// QKV tile slower (R13: occupancy counter pinned ~31% regardless of
// residency — the vmcnt(0)-drain serialization is the floor, not a
// residency problem). R12 config = session best (171.5us).
// MAP: XCD-tiled bijective remaps (launch id mod 8 = XCD, validated R7):
//   MAP=1 QKV 24x32: 8m x 12n per XCD (A 2MB + B 3MB ~ L2; FETCH 36->21MB)
//   MAP=2 proj 8x64: all-n x 8m per XCD (A 1MB + B 2MB fits)
template<int EPI, int BM_, int BN_, int MAP>
__global__ __launch_bounds__(256)
void gemm_bt(const unsigned short* __restrict__ Ab, const unsigned short* __restrict__ Wb,
             const float* __restrict__ bias, float* __restrict__ outp,
             int K, int N,
             unsigned short* __restrict__ qo, unsigned short* __restrict__ ko,
             unsigned short* __restrict__ vo)
{
  constexpr int WM = BM_ / 2, WN = BN_ / 2;
  constexpr int NI = WM / 16;          // A-frags / acc rows per wave
  constexpr int NJ = WN / 16;          // B-frags / acc cols per wave
  constexpr int NAI = BM_ / 32;        // A staging issues/thread
  constexpr int NBI = BN_ / 32;        // B staging issues/thread
  __shared__ unsigned short As[2 * BM_ * 32];   // [panel][row][col]
  __shared__ unsigned short Bs[2 * BN_ * 32];

  const int t = threadIdx.x;
  const int lane = t & 63, w = t >> 6;

  // XCD-tiled bijective block remap (launch id mod 8 = XCD, validated R7).
  int bx = (int)blockIdx.x, by = (int)blockIdx.y;
  if (MAP == 1) {                      // QKV: 24x32 grid -> 8mx12n per XCD
    int lin = by * 24 + bx;
    int c = lin & 7, u = lin >> 3;     // u in [0,96)
    by = (c & 3) * 8 + (u & 7);
    bx = (c >> 2) * 12 + (u >> 3);
  } else if (MAP == 2) {               // proj: 8x64 grid -> 8m x all-n per XCD
    int lin = by * 8 + bx;
    int c = lin & 7, u = lin >> 3;     // u in [0,64)
    by = c * 8 + (u & 7);
    bx = u >> 3;
  }
  const int m0 = by * BM_, n0 = bx * BN_;
  const int fr = lane & 15, qd = lane >> 4;
  const int wm = (w >> 1) * WM, wn = (w & 1) * WN;

  f32x4 acc[NI][NJ] = {};

  for (int k0 = 0; k0 < K; k0 += 64) {
    __syncthreads();
    #pragma unroll
    for (int j = 0; j < NAI; j++) {          // A: BM_*8 granules of 16B
      int G = j * 256 + t;
      int panel = G / (BM_ * 4), rowg = (G / 4) % BM_, colg = G & 3;
      async_cp16(Ab + (size_t)(m0 + rowg) * K + k0 + panel * 32 + colg * 8, &As[G * 8]);
    }
    #pragma unroll
    for (int j = 0; j < NBI; j++) {          // B: BN_*8 granules
      int G = j * 256 + t;
      int panel = G / (BN_ * 4), rowg = (G / 4) % BN_, colg = G & 3;
      async_cp16(Wb + (size_t)(n0 + rowg) * K + k0 + panel * 32 + colg * 8, &Bs[G * 8]);
    }
    __syncthreads();
    #pragma unroll
    for (int kh = 0; kh < 2; kh++) {
      short8 af[NI], bf[NJ];
      #pragma unroll
      for (int ib = 0; ib < NI; ib++)
        af[ib] = *(const short8*)&As[kh * (BM_ * 32) + (wm + ib * 16 + fr) * 32 + qd * 8];
      #pragma unroll
      for (int jb = 0; jb < NJ; jb++)
        bf[jb] = *(const short8*)&Bs[kh * (BN_ * 32) + (wn + jb * 16 + fr) * 32 + qd * 8];
      #pragma unroll
      for (int ib = 0; ib < NI; ib++)
        #pragma unroll
        for (int jb = 0; jb < NJ; jb++)
          acc[ib][jb] = __builtin_amdgcn_mfma_f32_16x16x32_bf16(af[ib], bf[jb], acc[ib][jb], 0, 0, 0);
    }
  }

  #pragma unroll
  for (int jb = 0; jb < NJ; jb++) {
    int col = n0 + wn + jb * 16 + fr;
    float bv = bias[col];
    if (EPI == 0) {
      int which = col >> 10;       // uniform per block (BN divides 1024)
      int rem = col & 1023;
      int hh = rem >> 6, dd = rem & 63;
      #pragma unroll
      for (int ib = 0; ib < NI; ib++) {
        int row4 = m0 + wm + ib * 16 + qd * 4;
        int bb = row4 >> 11, tt = row4 & (Tq - 1);
        if (which == 2) {
          unsigned lo = (unsigned)f2bf(acc[ib][jb][0] + bv)
                      | ((unsigned)f2bf(acc[ib][jb][1] + bv) << 16);
          unsigned hi = (unsigned)f2bf(acc[ib][jb][2] + bv)
                      | ((unsigned)f2bf(acc[ib][jb][3] + bv) << 16);
          uint2 pk; pk.x = lo; pk.y = hi;
          *(uint2*)&vo[((size_t)(bb * Hq + hh) * HDq + dd) * Tq + tt] = pk;
        } else {
          unsigned short* dst = (which == 0) ? qo : ko;
          float scl = (which == 0) ? QSCL : 1.0f;
          #pragma unroll
          for (int r = 0; r < 4; r++)
            dst[((size_t)(bb * Hq + hh) * Tq + tt + r) * HDq + dd] =
                f2bf((acc[ib][jb][r] + bv) * scl);
        }
      }
    } else {
      #pragma unroll
      for (int ib = 0; ib < NI; ib++)
        #pragma unroll
        for (int r = 0; r < 4; r++) {
          int row = m0 + wm + ib * 16 + qd * 4 + r;
          outp[(size_t)row * N + col] = acc[ib][jb][r] + bv;
        }
    }
  }
}

// ---------------- MFMA flash attention: in-register softmax ------------------
// R7 kernel (best measured: ~42us). Structure log: dual-strip 2/CU = 56.8us
// twice (R0,R5); balance remap no-op (R6); split-K w/ device fences disaster
// (R8); no-LDS direct-global 125us (R9 — L1 thrash). ONE 64-row strip per
// block, 1024 blocks = 4/CU; XCD-grouped bh keeps K/V L2-resident (R7:
// FETCH 63->12MB). Swapped QK^T + cvt_pk/permlane in-register softmax;
// P never touches LDS.

template<bool DIAG>
__device__ __forceinline__ void strip_iter(
    const unsigned short* __restrict__ Ksb, const unsigned short* __restrict__ Vtsb,
    const short8 (&aq)[2], const short8 ones,
    int fr, int qd, int off0, int off1, int thr,
    f32x4 (&oacc)[4], f32x4& lacc)
{
  short8 bk[4][2];
  #pragma unroll
  for (int nb = 0; nb < 4; nb++) {
    bk[nb][0] = *(const short8*)&Ksb[(nb * 16 + fr) * 64 + off0];
    bk[nb][1] = *(const short8*)&Ksb[(nb * 16 + fr) * 64 + off1];
  }
  f32x4 s4[4] = {};
  __builtin_amdgcn_s_setprio(1);
  #pragma unroll
  for (int nb = 0; nb < 4; nb++)
    s4[nb] = __builtin_amdgcn_mfma_f32_16x16x32_bf16(bk[nb][0], aq[0], s4[nb], 0, 0, 0);
  #pragma unroll
  for (int nb = 0; nb < 4; nb++)
    s4[nb] = __builtin_amdgcn_mfma_f32_16x16x32_bf16(bk[nb][1], aq[1], s4[nb], 0, 0, 0);
  __builtin_amdgcn_s_setprio(0);

  unsigned x[4][2];
  #pragma unroll
  for (int nb = 0; nb < 4; nb++) {
    float p[4];
    #pragma unroll
    for (int reg = 0; reg < 4; reg++) {
      p[reg] = exp2f(s4[nb][reg]);
      if (DIAG && (nb * 16 + qd * 4 + reg) > thr) p[reg] = 0.f;
    }
    asm("v_cvt_pk_bf16_f32 %0, %1, %2" : "=v"(x[nb][0]) : "v"(p[0]), "v"(p[1]));
    asm("v_cvt_pk_bf16_f32 %0, %1, %2" : "=v"(x[nb][1]) : "v"(p[2]), "v"(p[3]));
  }
  permswap(x[0][0], x[1][0]);
  permswap(x[0][1], x[1][1]);
  permswap(x[2][0], x[3][0]);
  permswap(x[2][1], x[3][1]);

  short8 ap0, ap1;
  {
    union { unsigned u[4]; short8 s; } c0, c1;
    c0.u[0] = x[0][0]; c0.u[1] = x[0][1]; c0.u[2] = x[1][0]; c0.u[3] = x[1][1];
    c1.u[0] = x[2][0]; c1.u[1] = x[2][1]; c1.u[2] = x[3][0]; c1.u[3] = x[3][1];
    ap0 = c0.s; ap1 = c1.s;
  }

  short8 bv[4][2];
  #pragma unroll
  for (int db = 0; db < 4; db++) {
    bv[db][0] = *(const short8*)&Vtsb[(db * 16 + fr) * 64 + off0];
    bv[db][1] = *(const short8*)&Vtsb[(db * 16 + fr) * 64 + off1];
  }
  __builtin_amdgcn_s_setprio(1);
  lacc = __builtin_amdgcn_mfma_f32_16x16x32_bf16(ap0, ones, lacc, 0, 0, 0);
  lacc = __builtin_amdgcn_mfma_f32_16x16x32_bf16(ap1, ones, lacc, 0, 0, 0);
  #pragma unroll
  for (int db = 0; db < 4; db++) {
    oacc[db] = __builtin_amdgcn_mfma_f32_16x16x32_bf16(ap0, bv[db][0], oacc[db], 0, 0, 0);
    oacc[db] = __builtin_amdgcn_mfma_f32_16x16x32_bf16(ap1, bv[db][1], oacc[db], 0, 0, 0);
  }
  __builtin_amdgcn_s_setprio(0);
}

__global__ __launch_bounds__(256, 4)
void attn_fwd(const unsigned short* __restrict__ qb, const unsigned short* __restrict__ kb,
              const unsigned short* __restrict__ vtb, unsigned short* __restrict__ ab)
{
  __shared__ unsigned short Ks[2][64 * 64];    // 2 x 8 KB, swizzled
  __shared__ unsigned short Vts[2][64 * 64];   // 2 x 8 KB, swizzled (V^T [d][c])

  const int t = threadIdx.x, w = t >> 6, lane = t & 63;
  const int fr = lane & 15, qd = lane >> 4;

  // XCD-grouped (bh, strip) assignment (validated R7: K/V L2-resident).
  const int L  = (int)blockIdx.x;              // 0..1023
  const int c  = L & 7;                        // XCD (launch id mod 8)
  const int i  = L >> 3;                       // 0..127 within XCD
  const int q4 = i >> 5, j = i & 31;
  const int bh = c + 8 * q4;                   // 4 bh per XCD -> K/V L2-fit
  const int s  = (q4 & 1) ? j : 31 - j;        // balanced, long strips early
  const int s0 = s * 64;
  const int thr = w * 16 + fr;                 // this lane's q (strip-local)

  short8 aq[2];
  const unsigned short* Qg = qb + ((size_t)bh * Tq + s0) * HDq;
  #pragma unroll
  for (int cc = 0; cc < 2; cc++)
    aq[cc] = *(const short8*)(Qg + (w * 16 + fr) * 64 + cc * 32 + qd * 8);

  const unsigned short* Kbh = kb + (size_t)bh * Tq * HDq;
  const unsigned short* Vbh = vtb + (size_t)bh * HDq * Tq;

  const int off0 = ((qd ^ (fr & 7)) * 8);
  const int off1 = off0 ^ 32;

  const int G0 = 2 * w * 64 + lane, G1 = G0 + 64;
  const int r0 = G0 >> 3, g0 = (G0 & 7) ^ (r0 & 7);
  const int r1 = G1 >> 3, g1 = (G1 & 7) ^ (r1 & 7);

  short8 ones;
  #pragma unroll
  for (int jj = 0; jj < 8; jj++) ones[jj] = (short)0x3F80;  // bf16 1.0

  f32x4 oacc[4] = {};
  f32x4 lacc = {};

  async_cp16(Kbh + (size_t)r0 * 64 + g0 * 8, &Ks[0][G0 * 8]);
  async_cp16(Vbh + (size_t)r0 * Tq + g0 * 8, &Vts[0][G0 * 8]);
  async_cp16(Kbh + (size_t)r1 * 64 + g1 * 8, &Ks[0][G1 * 8]);
  async_cp16(Vbh + (size_t)r1 * Tq + g1 * 8, &Vts[0][G1 * 8]);

  for (int kt = 0; kt < s; kt++) {
    const int cur = kt & 1, nxt = cur ^ 1;
    __syncthreads();   // drains buf[cur] loads (in flight during prior compute)
    const size_t kofs = (size_t)(kt + 1) * 64;
    async_cp16(Kbh + (kofs + r0) * 64 + g0 * 8, &Ks[nxt][G0 * 8]);
    async_cp16(Vbh + (size_t)r0 * Tq + kofs + g0 * 8, &Vts[nxt][G0 * 8]);
    async_cp16(Kbh + (kofs + r1) * 64 + g1 * 8, &Ks[nxt][G1 * 8]);
    async_cp16(Vbh + (size_t)r1 * Tq + kofs + g1 * 8, &Vts[nxt][G1 * 8]);
    strip_iter<false>(Ks[cur], Vts[cur], aq, ones, fr, qd, off0, off1, thr, oacc, lacc);
  }
  __syncthreads();
  strip_iter<true>(Ks[s & 1], Vts[s & 1], aq, ones, fr, qd, off0, off1, thr, oacc, lacc);

  #pragma unroll
  for (int reg = 0; reg < 4; reg++) {
    float linv = 1.0f / lacc[reg];
    size_t rowoff = ((size_t)(bh >> 4) * Tq + s0 + w * 16 + qd * 4 + reg) * Dq
                  + (bh & 15) * HDq;
    #pragma unroll
    for (int db = 0; db < 4; db++)
      ab[rowoff + db * 16 + fr] = f2bf(oacc[db][reg] * linv);
  }
}

extern "C" void kernel_launch(void* const* d_in, const int* in_sizes, int n_in,
                              void* d_out, int out_size, void* d_ws, size_t ws_size,
                              hipStream_t stream) {
  const float* x      = (const float*)d_in[0];
  const float* w_qkv  = (const float*)d_in[1];
  const float* b_qkv  = (const float*)d_in[2];
  const float* w_proj = (const float*)d_in[3];
  const float* b_proj = (const float*)d_in[4];
  float* out = (float*)d_out;

  unsigned short* ws = (unsigned short*)d_ws;
  const size_t NE = (size_t)Bq * Hq * Tq * HDq;   // 4,194,304
  unsigned short* qb  = ws;
  unsigned short* kb  = ws + NE;
  unsigned short* vtb = ws + 2 * NE;   // V^T: [B,H,HD,T]
  unsigned short* ab  = ws + 3 * NE;
  unsigned short* xb  = ws + 4 * NE;             // bf16 x      [4096,1024]
  unsigned short* wqb = xb + (size_t)NXC * 8;    // bf16 w_qkv  [3072,1024]
  unsigned short* wpb = wqb + (size_t)NW1C * 8;  // bf16 w_proj [1024,1024]

  dim3 blk(256);
  cvt_all<<<dim3((NXC + NW1C + NW2C) >> 9), blk, 0, stream>>>(x, w_qkv, w_proj, xb, wqb, wpb);

  dim3 g1(3 * Dq / 128, Bq * Tq / 128);   // 24 x 32 (QKV: 128x128, XCD-tiled)
  gemm_bt<0, 128, 128, 1><<<g1, blk, 0, stream>>>(xb, wqb, b_qkv, nullptr,
                                                  Dq, 3 * Dq, qb, kb, vtb);

  dim3 g2(1024);                          // XCD-grouped bh (R7, best measured)
  attn_fwd<<<g2, blk, 0, stream>>>(qb, kb, vtb, ab);

  dim3 g3(Dq / 128, Bq * Tq / 64);        // 8 x 64  (proj: 64x128, XCD-tiled)
  gemm_bt<1, 64, 128, 2><<<g3, blk, 0, stream>>>(ab, wpb, b_proj, out,
                                                 Dq, Dq, nullptr, nullptr, nullptr);
}